// Round 6
// baseline (220.806 us; speedup 1.0000x reference)
//
#include <hip/hip_runtime.h>
#include <math.h>

// IDMRFLoss on MI355X — R17: 16B-granular sim layout. R16 budget analysis:
// colsum+rowmax (2x 143.6MB sim reads) ran at ~3 TB/s because the old sim
// layout forced 8B/lane ushort4 reads. New per-block layout puts 8 same-q
// p-values in each 16B chunk:
//   elem = slot*4096 + (t2*4+u)*512 + quad*128 + lm*8 + th*4 + r  (t=2*t2+th)
//   p = by*128+(slot&1)*64+t2*32+th*16+quad*4+r ; q = bx*128+(slot>>1)*64+u*16+lm
// -> gemm stores, colsum reads, rowmax reads are ALL 16B/lane, 1KB/wave.
// rowmax becomes G-split partials + rmreduce (R15-proven reduction order).
// + T1 XCD swizzle on prep (input line sharing) and gemm (A-panel L2 reuse).
// prep/gemm-core/colmax_reduce/finalize unchanged from R16 (219.1us).
//
// Layer 0 (relu3_2): B=4, C=256, S=4096, weight 1.0
// Layer 1 (relu4_2): B=4, C=512, S=1024, weight 2.0 (style + content)
//
// Swizzled operand layout (per batch, matrix [S][K] bf16):
//   elem(row,k) at ((row>>4)*(K/8) + (k>>3))*128 + (row&15)*8 + (k&7)
//
// Math (per combo): c1 = 1/((1-colmax)/2+eps); log2 domain c1L=c1*log2e,
// c0L=(2-c1)*log2e; colsum_q = sum_p 2^(c0L+c1L*v);
// kmax_p = 2^(max_q (c0L - log2(colsum_q) + c1L*v)); loss = sum -w*log(mean kmax).

#define MRF_EPS 1e-5f
#define LOG2E 1.44269504088896340736f

typedef __attribute__((ext_vector_type(8))) short bf16x8;
typedef __attribute__((ext_vector_type(4))) float f32x4;
typedef unsigned short ushort_t;
struct __align__(8) ushort4_t { ushort_t x, y, z, w; };
struct __align__(16) ushort8_t { ushort_t v[8]; };

__device__ __forceinline__ ushort_t f2bf(float x) {
    unsigned u = __float_as_uint(x);
    u += 0x7FFFu + ((u >> 16) & 1u);
    return (ushort_t)(u >> 16);
}
__device__ __forceinline__ float bf2f(ushort_t u) {
    return __uint_as_float(((unsigned)u) << 16);
}

// async global->LDS, 16B per lane. LDS dest is wave-uniform base + lane*16.
typedef __attribute__((address_space(1))) const unsigned int gu32;
typedef __attribute__((address_space(3))) unsigned int lu32;
__device__ __forceinline__ void gload16(const ushort_t* g, ushort_t* l) {
    __builtin_amdgcn_global_load_lds((gu32*)(uintptr_t)g, (lu32*)(uintptr_t)l,
                                     16, 0, 0);
}

// ===== prep: fused stats+apply (one input pass, data held in registers) =====
template <int C>
__device__ __forceinline__ void prep_body(
    const float* __restrict__ gen, const float* __restrict__ tar,
    ushort_t* __restrict__ gnT, ushort_t* __restrict__ tnT,
    int S, int b, int bx, char* __restrict__ smem) {
    constexpr int KN = C / 64;   // f32x4 loads per thread per tensor
    constexpr int KC = C / 8;    // swizzle chunks
    constexpr int CP = C + 8;    // padded LDS tile stride (elems)
    const int tid = threadIdx.x, pq = tid & 3, cs = tid >> 2;
    const int s0 = bx * 16;

    f32x4* red  = (f32x4*)smem;            // [4][4][64], 16 KB (dead after stats)
    f32x4* red2 = (f32x4*)(smem + 16384);  // [4][4][4]
    ushort_t* tileG = (ushort_t*)smem;     // [16][CP] bf16 — aliases red region
    ushort_t* tileT = tileG + 16 * CP;
    float* sm  = (float*)(smem + 33280);   // [16] mean (beyond tile region)
    float* srt = sm + 16;                  // [16] rsqrt var_t
    float* srg = sm + 32;                  // [16] rsqrt var_g

    const float* g = gen + (size_t)b * C * S + s0 + pq * 4;
    const float* t = tar + (size_t)b * C * S + s0 + pq * 4;

    f32x4 gv[KN], tv[KN];
    f32x4 st = {0.f, 0.f, 0.f, 0.f}, st2 = st, sg = st, sg2 = st;
#pragma unroll
    for (int k = 0; k < KN; k++) {          // c = cs + 64k, ascending (== old order)
        tv[k] = *(const f32x4*)(t + (size_t)(cs + 64 * k) * S);
        gv[k] = *(const f32x4*)(g + (size_t)(cs + 64 * k) * S);
        st += tv[k]; st2 += tv[k] * tv[k]; sg += gv[k]; sg2 += gv[k] * gv[k];
    }
    red[(0 * 4 + pq) * 64 + cs] = st;  red[(1 * 4 + pq) * 64 + cs] = st2;
    red[(2 * 4 + pq) * 64 + cs] = sg;  red[(3 * 4 + pq) * 64 + cs] = sg2;
    __syncthreads();
    if (tid < 64) {
        int s_ = tid >> 4, p_ = (tid >> 2) & 3, part = tid & 3;
        f32x4 s = red[(s_ * 4 + p_) * 64 + part * 16];
#pragma unroll
        for (int j = 1; j < 16; j++) s += red[(s_ * 4 + p_) * 64 + part * 16 + j];
        red2[(s_ * 4 + p_) * 4 + part] = s;
    }
    __syncthreads();
    if (tid < 4) {
        f32x4 sts  = red2[(0*4+tid)*4+0] + red2[(0*4+tid)*4+1] + red2[(0*4+tid)*4+2] + red2[(0*4+tid)*4+3];
        f32x4 st2s = red2[(1*4+tid)*4+0] + red2[(1*4+tid)*4+1] + red2[(1*4+tid)*4+2] + red2[(1*4+tid)*4+3];
        f32x4 sgs  = red2[(2*4+tid)*4+0] + red2[(2*4+tid)*4+1] + red2[(2*4+tid)*4+2] + red2[(2*4+tid)*4+3];
        f32x4 sg2s = red2[(3*4+tid)*4+0] + red2[(3*4+tid)*4+1] + red2[(3*4+tid)*4+2] + red2[(3*4+tid)*4+3];
        f32x4 m, vrt, vrg;
        float invC = 1.f / (float)C;
#pragma unroll
        for (int e = 0; e < 4; e++) {
            float mm = sts[e] * invC;
            m[e] = mm;
            vrt[e] = rsqrtf(st2s[e] - mm * sts[e]);
            vrg[e] = rsqrtf(sg2s[e] - 2.f * mm * sgs[e] + mm * sts[e]);
        }
        *(f32x4*)&sm[tid * 4] = m;
        *(f32x4*)&srt[tid * 4] = vrt;
        *(f32x4*)&srg[tid * 4] = vrg;
    }
    __syncthreads();   // red/red2 dead; tile region may now be written
    f32x4 m4  = *(f32x4*)&sm[pq * 4];
    f32x4 rt4 = *(f32x4*)&srt[pq * 4];
    f32x4 rg4 = *(f32x4*)&srg[pq * 4];
#pragma unroll
    for (int k = 0; k < KN; k++) {
        int c = cs + 64 * k;
#pragma unroll
        for (int e = 0; e < 4; e++) {
            tileG[(pq * 4 + e) * CP + c] = f2bf((gv[k][e] - m4[e]) * rg4[e]);
            tileT[(pq * 4 + e) * CP + c] = f2bf((tv[k][e] - m4[e]) * rt4[e]);
        }
    }
    __syncthreads();
    const int lm = tid & 15;
    const int r16 = s0 >> 4;
    size_t obase = (size_t)b * (size_t)S * C;
#pragma unroll
    for (int j = 0; j < KC / 16; j++) {
        int ch = (tid >> 4) + 16 * j;
        size_t off = obase + (((size_t)r16 * KC + ch) * 16 + lm) * 8;
        *(ushort8_t*)(gnT + off) = *(const ushort8_t*)&tileG[lm * CP + ch * 8];
        *(ushort8_t*)(tnT + off) = *(const ushort8_t*)&tileT[lm * CP + ch * 8];
    }
}

__global__ __launch_bounds__(256) void prep_all(
    const float* __restrict__ gen3, const float* __restrict__ tar3,
    const float* __restrict__ gen4, const float* __restrict__ tar4,
    ushort_t* __restrict__ gnT3, ushort_t* __restrict__ tnT3,
    ushort_t* __restrict__ gnT4, ushort_t* __restrict__ tnT4) {
    __shared__ __align__(16) char smem[33536];
    int bid = (blockIdx.x & 7) * 160 + (blockIdx.x >> 3);   // XCD swizzle (1280=8*160)
    if (bid < 256) {            // layer4: 4 z * 64 row-groups
        int z = bid >> 6, bx = bid & 63;
        prep_body<512>(gen4, tar4, gnT4, tnT4, 1024, z, bx, smem);
    } else {                    // layer3: 4 z * 256 row-groups
        bid -= 256;
        int z = bid >> 8, bx = bid & 255;
        prep_body<256>(gen3, tar3, gnT3, tnT3, 4096, z, bx, smem);
    }
}

// ===== gemm (R14 core; epilogue writes paired ushort8 in the new layout) =====
template <int K>
__device__ __forceinline__ void gemm_body(
    const ushort_t* __restrict__ A, const ushort_t* __restrict__ B,
    ushort_t* __restrict__ sim, float* __restrict__ cmPart,
    int S, int bx, int by, ushort_t* __restrict__ lds) {
    const int tid = threadIdx.x;
    const int lane = tid & 63, wave = tid >> 6;
    const int wm = (wave & 1) * 64, wn = (wave >> 1) * 64;
    const int lm = lane & 15, quad = lane >> 4;
    const int q0 = bx * 128;

    constexpr int KC = K / 8;
    constexpr int KB = K / 32;

    const ushort_t* segsrc[4];
    ushort_t* segdst[4];
#pragma unroll
    for (int i = 0; i < 4; i++) {
        int s = wave * 4 + i;
        segsrc[i] = (s < 8)
            ? A + ((size_t)(by * 8 + s) * KC) * 128 + lane * 8
            : B + ((size_t)(bx * 8 + (s - 8)) * KC) * 128 + lane * 8;
        segdst[i] = lds + s * 512;
    }

    auto stage = [&](int buf, int kb) {
#pragma unroll
        for (int i = 0; i < 4; i++)
            gload16(segsrc[i] + (size_t)kb * 512, segdst[i] + buf * 8192);
    };

    f32x4 acc[4][4];
#pragma unroll
    for (int t = 0; t < 4; t++)
#pragma unroll
        for (int u = 0; u < 4; u++) acc[t][u] = (f32x4){0.f, 0.f, 0.f, 0.f};

    stage(0, 0);
    stage(1, 1);
    asm volatile("s_waitcnt vmcnt(4)" ::: "memory");
    __builtin_amdgcn_s_barrier();
    __builtin_amdgcn_sched_barrier(0);

    const ushort_t* lA = lds + (wm >> 4) * 512 + quad * 128 + lm * 8;
    const ushort_t* lB = lds + 4096 + (wn >> 4) * 512 + quad * 128 + lm * 8;

#pragma unroll
    for (int kb = 0; kb < KB; kb++) {
        const int cur = (kb % 3) * 8192;
        if (kb + 2 < KB) stage((kb + 2) % 3, kb + 2);
        bf16x8 a[4], b[4];
#pragma unroll
        for (int t = 0; t < 4; t++) {
            a[t] = *(const bf16x8*)(lA + cur + t * 512);
            b[t] = *(const bf16x8*)(lB + cur + t * 512);
        }
        __builtin_amdgcn_s_setprio(1);
#pragma unroll
        for (int t = 0; t < 4; t++)
#pragma unroll
            for (int u = 0; u < 4; u++)
                acc[t][u] = __builtin_amdgcn_mfma_f32_16x16x32_bf16(a[t], b[u], acc[t][u], 0, 0, 0);
        __builtin_amdgcn_s_setprio(0);
        if (kb + 1 < KB) {
            if (kb + 2 < KB) asm volatile("s_waitcnt vmcnt(4)" ::: "memory");
            else             asm volatile("s_waitcnt vmcnt(0)" ::: "memory");
            __builtin_amdgcn_s_barrier();
            __builtin_amdgcn_sched_barrier(0);
        }
    }

    int nQB = S >> 7;
    size_t base = ((size_t)(by * nQB + bx)) * 16384
                + (size_t)(wave * 4096 + quad * 128 + lm * 8);
    float cmax[4] = {-INFINITY, -INFINITY, -INFINITY, -INFINITY};
#pragma unroll
    for (int t2 = 0; t2 < 2; t2++)
#pragma unroll
        for (int u = 0; u < 4; u++) {
            f32x4 v0 = acc[t2 * 2][u], v1 = acc[t2 * 2 + 1][u];
            ushort8_t o;
            o.v[0] = f2bf(v0.x); o.v[1] = f2bf(v0.y); o.v[2] = f2bf(v0.z); o.v[3] = f2bf(v0.w);
            o.v[4] = f2bf(v1.x); o.v[5] = f2bf(v1.y); o.v[6] = f2bf(v1.z); o.v[7] = f2bf(v1.w);
            *(ushort8_t*)(sim + base + (t2 * 4 + u) * 512) = o;
            float mx = fmaxf(fmaxf(fmaxf(bf2f(o.v[0]), bf2f(o.v[1])), fmaxf(bf2f(o.v[2]), bf2f(o.v[3]))),
                             fmaxf(fmaxf(bf2f(o.v[4]), bf2f(o.v[5])), fmaxf(bf2f(o.v[6]), bf2f(o.v[7]))));
            cmax[u] = fmaxf(cmax[u], mx);
        }
    int r = by * 2 + (wave & 1);
#pragma unroll
    for (int u = 0; u < 4; u++) {
        float m = cmax[u];
        m = fmaxf(m, __shfl_xor(m, 16, 64));
        m = fmaxf(m, __shfl_xor(m, 32, 64));
        if (lane < 16) cmPart[(size_t)r * S + q0 + wn + u * 16 + lane] = m;
    }
}

__global__ __launch_bounds__(256) void gemm_all(
    const ushort_t* __restrict__ tnT3, const ushort_t* __restrict__ gnT3,
    ushort_t* __restrict__ sim3, float* __restrict__ cmPart3,
    const ushort_t* __restrict__ tnT4, const ushort_t* __restrict__ gnT4,
    ushort_t* __restrict__ sim4, float* __restrict__ cmPart4) {
    __shared__ ushort_t lds[24576];   // 3 bufs x (A 8KB + B 8KB) = 48 KB
    int bid = (blockIdx.x & 7) * 544 + (blockIdx.x >> 3);   // XCD swizzle (4352=8*544)
    if (bid < 256) {            // layer4 (2x K per block)
        int z = bid >> 6, rem = bid & 63, by = rem >> 3, bx = rem & 7;
        gemm_body<512>(tnT4 + (size_t)z * 524288, gnT4 + (size_t)z * 524288,
                       sim4 + (size_t)z * 1048576, cmPart4 + (size_t)z * 16384,
                       1024, bx, by, lds);
    } else {
        bid -= 256;
        int z = bid >> 10, rem = bid & 1023, by = rem >> 5, bx = rem & 31;
        gemm_body<256>(tnT3 + (size_t)z * 1048576, gnT3 + (size_t)z * 1048576,
                       sim3 + (size_t)z * 16777216, cmPart3 + (size_t)z * 262144,
                       4096, bx, by, lds);
    }
}

// ================= colmax reduce -> coef, zero colsum + acc =================
__global__ __launch_bounds__(256) void colmax_reduce_all(
    const float* __restrict__ cmPart3, float2* __restrict__ coef3, float* __restrict__ colsum3,
    const float* __restrict__ cmPart4, float2* __restrict__ coef4, float* __restrict__ colsum4,
    float* __restrict__ acc) {
    const float* cmPart; float2* coef; float* colsum; int S, R, qb, accIdx;
    int bid = blockIdx.x;
    if (bid < 16) {             // layer4: 4 z * 4 blocks
        int z = bid >> 2; qb = bid & 3; S = 1024; R = 16; accIdx = 4 + z;
        cmPart = cmPart4 + (size_t)z * 16384; coef = coef4 + (size_t)z * 1024;
        colsum = colsum4 + (size_t)z * 1024;
    } else {
        bid -= 16;
        int z = bid >> 4; qb = bid & 15; S = 4096; R = 64; accIdx = z;
        cmPart = cmPart3 + (size_t)z * 262144; coef = coef3 + (size_t)z * 4096;
        colsum = colsum3 + (size_t)z * 4096;
    }
    if (qb == 0 && threadIdx.x == 0) acc[accIdx] = 0.f;
    int q = qb * 256 + threadIdx.x;
    float m = cmPart[q];
    for (int r = 1; r < R; r++) m = fmaxf(m, cmPart[(size_t)r * S + q]);
    float c1 = 1.f / ((1.f - m) * 0.5f + MRF_EPS);
    coef[q] = make_float2((2.f - c1) * LOG2E, c1 * LOG2E);
    colsum[q] = 0.f;
}

// ================= colsum (16B reads, 1KB/wave) =================
__global__ __launch_bounds__(256) void colsum_all(
    const ushort_t* __restrict__ sim3, const float2* __restrict__ coef3, float* __restrict__ colsum3,
    const ushort_t* __restrict__ sim4, const float2* __restrict__ coef4, float* __restrict__ colsum4) {
    const ushort_t* sim; const float2* coef; float* colsum; int S, bx, by;
    int bid = blockIdx.x;
    if (bid < 256) {            // layer4: 4 z * (8 x 8)
        int z = bid >> 6, rem = bid & 63; by = rem >> 3; bx = rem & 7; S = 1024;
        sim = sim4 + (size_t)z * 1048576; coef = coef4 + (size_t)z * 1024;
        colsum = colsum4 + (size_t)z * 1024;
    } else {
        bid -= 256;
        int z = bid >> 10, rem = bid & 1023; by = rem >> 5; bx = rem & 31; S = 4096;
        sim = sim3 + (size_t)z * 16777216; coef = coef3 + (size_t)z * 4096;
        colsum = colsum3 + (size_t)z * 4096;
    }
    int tid = threadIdx.x, lane = tid & 63;
    int quad = lane >> 4, lm = lane & 15;
    int sub = (tid >> 6) & 1, cg = tid >> 7;
    int slot = sub | (cg << 1);
    int nQB = S >> 7;
    int qb = bx * 128 + cg * 64 + lm;
    float c0[4], c1[4], su[4];
#pragma unroll
    for (int u = 0; u < 4; u++) {
        float2 cc = coef[qb + u * 16];
        c0[u] = cc.x; c1[u] = cc.y; su[u] = 0.f;
    }
    const ushort_t* base = sim + ((size_t)(by * nQB + bx)) * 16384
                         + (size_t)(slot * 4096 + quad * 128 + lm * 8);
#pragma unroll
    for (int t2 = 0; t2 < 2; t2++)
#pragma unroll
        for (int u = 0; u < 4; u++) {
            ushort8_t e = *(const ushort8_t*)(base + (t2 * 4 + u) * 512);
            float s = 0.f;
#pragma unroll
            for (int j = 0; j < 8; j++) s += exp2f(c0[u] + c1[u] * bf2f(e.v[j]));
            su[u] += s;
        }
#pragma unroll
    for (int u = 0; u < 4; u++) {
        su[u] += __shfl_xor(su[u], 16, 64);
        su[u] += __shfl_xor(su[u], 32, 64);
        if (lane < 16) atomicAdd(colsum + qb + u * 16, su[u]);
    }
}

// ======= rowmax (16B reads, 1KB/wave; G-split bx, partials -> rmPart) =======
template <int NQB, int NBX>
__device__ __forceinline__ void rowmax_body(
    const ushort_t* __restrict__ sim, const float2* __restrict__ coef,
    const float* __restrict__ colsum, float* __restrict__ rmPart,
    int by, int g) {
    int tid = threadIdx.x, lane = tid & 63, wave = tid >> 6;
    int ph = wave & 1, t2 = wave >> 1;
    int quad = lane >> 4, lm = lane & 15;
    float m[8];
#pragma unroll
    for (int j = 0; j < 8; j++) m[j] = -INFINITY;
    for (int bxi = 0; bxi < NBX; bxi++) {
        int bx = g * NBX + bxi;
        float c0p[8], c1v[8];
#pragma unroll
        for (int cg = 0; cg < 2; cg++)
#pragma unroll
            for (int u = 0; u < 4; u++) {
                int q = bx * 128 + cg * 64 + u * 16 + lm;
                float2 cc = coef[q];
                c0p[cg * 4 + u] = cc.x - log2f(colsum[q]);
                c1v[cg * 4 + u] = cc.y;
            }
        const ushort_t* bb = sim + ((size_t)(by * NQB + bx)) * 16384
                           + (size_t)((t2 * 4) * 512 + quad * 128 + lm * 8);
#pragma unroll
        for (int cg = 0; cg < 2; cg++) {
            int slot = ph + 2 * cg;
#pragma unroll
            for (int u = 0; u < 4; u++) {
                ushort8_t e = *(const ushort8_t*)(bb + slot * 4096 + u * 512);
                float a = c0p[cg * 4 + u], c = c1v[cg * 4 + u];
#pragma unroll
                for (int j = 0; j < 8; j++) m[j] = fmaxf(m[j], a + c * bf2f(e.v[j]));
            }
        }
    }
    // reduce over the 16 lm lanes (they share the same p-set)
#pragma unroll
    for (int off = 1; off <= 8; off <<= 1)
#pragma unroll
        for (int j = 0; j < 8; j++) m[j] = fmaxf(m[j], __shfl_xor(m[j], off, 64));
    if (lm == 0) {
        int pbase = by * 128 + ph * 64 + t2 * 32 + quad * 4;
#pragma unroll
        for (int j = 0; j < 8; j++)
            rmPart[pbase + (j >> 2) * 16 + (j & 3)] = m[j];
    }
}

__global__ __launch_bounds__(256) void rowmax_all(
    const ushort_t* __restrict__ sim3, const float2* __restrict__ coef3, const float* __restrict__ colsum3,
    float* __restrict__ rmPart3,
    const ushort_t* __restrict__ sim4, const float2* __restrict__ coef4, const float* __restrict__ colsum4,
    float* __restrict__ rmPart4) {
    int bid = blockIdx.x;
    if (bid < 1024) {           // layer3: 4z * 32by * 8g
        int z = bid >> 8, rem = bid & 255, by = rem >> 3, g = rem & 7;
        rowmax_body<32, 4>(sim3 + (size_t)z * 16777216, coef3 + (size_t)z * 4096,
                           colsum3 + (size_t)z * 4096,
                           rmPart3 + ((size_t)(z * 8 + g)) * 4096, by, g);
    } else {                    // layer4: 4z * 8by * 4g
        bid -= 1024;
        int z = bid >> 5, rem = bid & 31, by = rem >> 2, g = rem & 3;
        rowmax_body<8, 2>(sim4 + (size_t)z * 1048576, coef4 + (size_t)z * 1024,
                          colsum4 + (size_t)z * 1024,
                          rmPart4 + ((size_t)(z * 4 + g)) * 1024, by, g);
    }
}

// ===== rowmax partial reduce -> exp2 -> acc =====
__global__ __launch_bounds__(256) void rmreduce_all(
    const float* __restrict__ rmPart3, const float* __restrict__ rmPart4,
    float* __restrict__ acc) {
    const float* rm; int G, stride, p; float* slot;
    int bid = blockIdx.x;
    if (bid < 64) {             // layer3: 4z * 16 blocks
        int z = bid >> 4, blk = bid & 15; G = 8; stride = 4096;
        rm = rmPart3 + (size_t)z * 8 * 4096;
        p = blk * 256 + threadIdx.x; slot = acc + z;
    } else {
        bid -= 64;              // layer4: 4z * 4 blocks
        int z = bid >> 2, blk = bid & 3; G = 4; stride = 1024;
        rm = rmPart4 + (size_t)z * 4 * 1024;
        p = blk * 256 + threadIdx.x; slot = acc + 4 + z;
    }
    float m = rm[p];
    for (int g = 1; g < G; g++) m = fmaxf(m, rm[(size_t)g * stride + p]);
    float k = exp2f(m);
#pragma unroll
    for (int off = 32; off >= 1; off >>= 1) k += __shfl_xor(k, off, 64);
    __shared__ float part[4];
    if ((threadIdx.x & 63) == 0) part[threadIdx.x >> 6] = k;
    __syncthreads();
    if (threadIdx.x == 0)
        atomicAdd(slot, part[0] + part[1] + part[2] + part[3]);
}

__global__ void finalize_kernel(const float* __restrict__ acc, float* __restrict__ out) {
    float loss = 0.f;
    for (int b = 0; b < 4; b++) loss += -logf(acc[b] * (1.f / 4096.f));
    for (int b = 0; b < 4; b++) loss += -2.f * logf(acc[4 + b] * (1.f / 1024.f));
    out[0] = loss;
}

extern "C" void kernel_launch(void* const* d_in, const int* in_sizes, int n_in,
                              void* d_out, int out_size, void* d_ws, size_t ws_size,
                              hipStream_t stream) {
    const float* gen3 = (const float*)d_in[0];
    const float* tar3 = (const float*)d_in[1];
    const float* gen4 = (const float*)d_in[2];
    const float* tar4 = (const float*)d_in[3];

    char* wsb = (char*)d_ws;
    size_t off = 0;
    auto alloc = [&](size_t bytes) {
        void* p = wsb + off;
        off += (bytes + 255) & ~(size_t)255;
        return p;
    };
    // layer3 (z=4): S=4096, C=256, R=64, nQB=32
    ushort_t* sim3 = (ushort_t*)alloc((size_t)4 * 16777216 * 2);   // 134.2 MB
    ushort_t* gnT3 = (ushort_t*)alloc((size_t)4 * 1048576 * 2);    // 8.4 MB
    ushort_t* tnT3 = (ushort_t*)alloc((size_t)4 * 1048576 * 2);    // 8.4 MB
    float* cmPart3 = (float*)alloc((size_t)4 * 262144 * 4);        // 4.2 MB
    float2* coef3 = (float2*)alloc((size_t)4 * 4096 * 8);
    float* colsum3 = (float*)alloc((size_t)4 * 4096 * 4);
    float* rmPart3 = (float*)alloc((size_t)4 * 8 * 4096 * 4);      // 512 KB
    // layer4 (z=4): S=1024, C=512, R=16, nQB=8
    ushort_t* sim4 = (ushort_t*)alloc((size_t)4 * 1048576 * 2);    // 8.4 MB
    ushort_t* gnT4 = (ushort_t*)alloc((size_t)4 * 524288 * 2);     // 4.2 MB
    ushort_t* tnT4 = (ushort_t*)alloc((size_t)4 * 524288 * 2);     // 4.2 MB
    float* cmPart4 = (float*)alloc((size_t)4 * 16384 * 4);
    float2* coef4 = (float2*)alloc((size_t)4 * 1024 * 8);
    float* colsum4 = (float*)alloc((size_t)4 * 1024 * 4);
    float* rmPart4 = (float*)alloc((size_t)4 * 4 * 1024 * 4);
    float* acc = (float*)alloc(64 * 4);
    // total ~173 MB (ws is 256 MiB)

    prep_all<<<256 + 1024, 256, 0, stream>>>(
        gen3, tar3, gen4, tar4, gnT3, tnT3, gnT4, tnT4);
    gemm_all<<<256 + 4096, 256, 0, stream>>>(
        tnT3, gnT3, sim3, cmPart3, tnT4, gnT4, sim4, cmPart4);
    colmax_reduce_all<<<16 + 64, 256, 0, stream>>>(
        cmPart3, coef3, colsum3, cmPart4, coef4, colsum4, acc);
    colsum_all<<<256 + 4096, 256, 0, stream>>>(
        sim3, coef3, colsum3, sim4, coef4, colsum4);
    rowmax_all<<<1024 + 128, 256, 0, stream>>>(
        sim3, coef3, colsum3, rmPart3, sim4, coef4, colsum4, rmPart4);
    rmreduce_all<<<64 + 16, 256, 0, stream>>>(rmPart3, rmPart4, acc);
    finalize_kernel<<<1, 1, 0, stream>>>(acc, (float*)d_out);
}

// Round 7
// 220.371 us; speedup vs baseline: 1.0020x; 1.0020x over previous
//
#include <hip/hip_runtime.h>
#include <math.h>

// IDMRFLoss on MI355X — R18: R17's 16B sim layout kept (colsum+rowmax ~11us
// faster); R17's XCD swizzles fixed. R17 post-mortem: global swizzle put all
// 256 layer4 gemm blocks (2x K work) on one XCD -> +13us tail; FETCH 56->35MB
// proved the L2-reuse mechanism works. R18: prep = identity order (no
// inter-block reuse, T1 null); gemm = balanced per-layer XCD chunking
// (each XCD: 32 L4 blocks first, then 512 consecutive L3 bids sharing
// A-panels). Bijective: [0,256) U [256,4352) partitioned exactly.
//
// sim per-128x128-block layout (16B-granular):
//   elem = slot*4096 + (t2*4+u)*512 + quad*128 + lm*8 + th*4 + r  (t=2*t2+th)
//   p = by*128+(slot&1)*64+t2*32+th*16+quad*4+r ; q = bx*128+(slot>>1)*64+u*16+lm
// Swizzled operand layout (per batch, matrix [S][K] bf16):
//   elem(row,k) at ((row>>4)*(K/8) + (k>>3))*128 + (row&15)*8 + (k&7)
//
// Math (per combo): c1 = 1/((1-colmax)/2+eps); log2 domain c1L=c1*log2e,
// c0L=(2-c1)*log2e; colsum_q = sum_p 2^(c0L+c1L*v);
// kmax_p = 2^(max_q (c0L - log2(colsum_q) + c1L*v)); loss = sum -w*log(mean kmax).

#define MRF_EPS 1e-5f
#define LOG2E 1.44269504088896340736f

typedef __attribute__((ext_vector_type(8))) short bf16x8;
typedef __attribute__((ext_vector_type(4))) float f32x4;
typedef unsigned short ushort_t;
struct __align__(8) ushort4_t { ushort_t x, y, z, w; };
struct __align__(16) ushort8_t { ushort_t v[8]; };

__device__ __forceinline__ ushort_t f2bf(float x) {
    unsigned u = __float_as_uint(x);
    u += 0x7FFFu + ((u >> 16) & 1u);
    return (ushort_t)(u >> 16);
}
__device__ __forceinline__ float bf2f(ushort_t u) {
    return __uint_as_float(((unsigned)u) << 16);
}

// async global->LDS, 16B per lane. LDS dest is wave-uniform base + lane*16.
typedef __attribute__((address_space(1))) const unsigned int gu32;
typedef __attribute__((address_space(3))) unsigned int lu32;
__device__ __forceinline__ void gload16(const ushort_t* g, ushort_t* l) {
    __builtin_amdgcn_global_load_lds((gu32*)(uintptr_t)g, (lu32*)(uintptr_t)l,
                                     16, 0, 0);
}

// ===== prep: fused stats+apply (one input pass, data held in registers) =====
template <int C>
__device__ __forceinline__ void prep_body(
    const float* __restrict__ gen, const float* __restrict__ tar,
    ushort_t* __restrict__ gnT, ushort_t* __restrict__ tnT,
    int S, int b, int bx, char* __restrict__ smem) {
    constexpr int KN = C / 64;   // f32x4 loads per thread per tensor
    constexpr int KC = C / 8;    // swizzle chunks
    constexpr int CP = C + 8;    // padded LDS tile stride (elems)
    const int tid = threadIdx.x, pq = tid & 3, cs = tid >> 2;
    const int s0 = bx * 16;

    f32x4* red  = (f32x4*)smem;            // [4][4][64], 16 KB (dead after stats)
    f32x4* red2 = (f32x4*)(smem + 16384);  // [4][4][4]
    ushort_t* tileG = (ushort_t*)smem;     // [16][CP] bf16 — aliases red region
    ushort_t* tileT = tileG + 16 * CP;
    float* sm  = (float*)(smem + 33280);   // [16] mean (beyond tile region)
    float* srt = sm + 16;                  // [16] rsqrt var_t
    float* srg = sm + 32;                  // [16] rsqrt var_g

    const float* g = gen + (size_t)b * C * S + s0 + pq * 4;
    const float* t = tar + (size_t)b * C * S + s0 + pq * 4;

    f32x4 gv[KN], tv[KN];
    f32x4 st = {0.f, 0.f, 0.f, 0.f}, st2 = st, sg = st, sg2 = st;
#pragma unroll
    for (int k = 0; k < KN; k++) {          // c = cs + 64k, ascending (== old order)
        tv[k] = *(const f32x4*)(t + (size_t)(cs + 64 * k) * S);
        gv[k] = *(const f32x4*)(g + (size_t)(cs + 64 * k) * S);
        st += tv[k]; st2 += tv[k] * tv[k]; sg += gv[k]; sg2 += gv[k] * gv[k];
    }
    red[(0 * 4 + pq) * 64 + cs] = st;  red[(1 * 4 + pq) * 64 + cs] = st2;
    red[(2 * 4 + pq) * 64 + cs] = sg;  red[(3 * 4 + pq) * 64 + cs] = sg2;
    __syncthreads();
    if (tid < 64) {
        int s_ = tid >> 4, p_ = (tid >> 2) & 3, part = tid & 3;
        f32x4 s = red[(s_ * 4 + p_) * 64 + part * 16];
#pragma unroll
        for (int j = 1; j < 16; j++) s += red[(s_ * 4 + p_) * 64 + part * 16 + j];
        red2[(s_ * 4 + p_) * 4 + part] = s;
    }
    __syncthreads();
    if (tid < 4) {
        f32x4 sts  = red2[(0*4+tid)*4+0] + red2[(0*4+tid)*4+1] + red2[(0*4+tid)*4+2] + red2[(0*4+tid)*4+3];
        f32x4 st2s = red2[(1*4+tid)*4+0] + red2[(1*4+tid)*4+1] + red2[(1*4+tid)*4+2] + red2[(1*4+tid)*4+3];
        f32x4 sgs  = red2[(2*4+tid)*4+0] + red2[(2*4+tid)*4+1] + red2[(2*4+tid)*4+2] + red2[(2*4+tid)*4+3];
        f32x4 sg2s = red2[(3*4+tid)*4+0] + red2[(3*4+tid)*4+1] + red2[(3*4+tid)*4+2] + red2[(3*4+tid)*4+3];
        f32x4 m, vrt, vrg;
        float invC = 1.f / (float)C;
#pragma unroll
        for (int e = 0; e < 4; e++) {
            float mm = sts[e] * invC;
            m[e] = mm;
            vrt[e] = rsqrtf(st2s[e] - mm * sts[e]);
            vrg[e] = rsqrtf(sg2s[e] - 2.f * mm * sgs[e] + mm * sts[e]);
        }
        *(f32x4*)&sm[tid * 4] = m;
        *(f32x4*)&srt[tid * 4] = vrt;
        *(f32x4*)&srg[tid * 4] = vrg;
    }
    __syncthreads();   // red/red2 dead; tile region may now be written
    f32x4 m4  = *(f32x4*)&sm[pq * 4];
    f32x4 rt4 = *(f32x4*)&srt[pq * 4];
    f32x4 rg4 = *(f32x4*)&srg[pq * 4];
#pragma unroll
    for (int k = 0; k < KN; k++) {
        int c = cs + 64 * k;
#pragma unroll
        for (int e = 0; e < 4; e++) {
            tileG[(pq * 4 + e) * CP + c] = f2bf((gv[k][e] - m4[e]) * rg4[e]);
            tileT[(pq * 4 + e) * CP + c] = f2bf((tv[k][e] - m4[e]) * rt4[e]);
        }
    }
    __syncthreads();
    const int lm = tid & 15;
    const int r16 = s0 >> 4;
    size_t obase = (size_t)b * (size_t)S * C;
#pragma unroll
    for (int j = 0; j < KC / 16; j++) {
        int ch = (tid >> 4) + 16 * j;
        size_t off = obase + (((size_t)r16 * KC + ch) * 16 + lm) * 8;
        *(ushort8_t*)(gnT + off) = *(const ushort8_t*)&tileG[lm * CP + ch * 8];
        *(ushort8_t*)(tnT + off) = *(const ushort8_t*)&tileT[lm * CP + ch * 8];
    }
}

__global__ __launch_bounds__(256) void prep_all(
    const float* __restrict__ gen3, const float* __restrict__ tar3,
    const float* __restrict__ gen4, const float* __restrict__ tar4,
    ushort_t* __restrict__ gnT3, ushort_t* __restrict__ tnT3,
    ushort_t* __restrict__ gnT4, ushort_t* __restrict__ tnT4) {
    __shared__ __align__(16) char smem[33536];
    int bid = blockIdx.x;        // identity (T1 null for prep: no inter-block reuse)
    if (bid < 256) {            // layer4: 4 z * 64 row-groups
        int z = bid >> 6, bx = bid & 63;
        prep_body<512>(gen4, tar4, gnT4, tnT4, 1024, z, bx, smem);
    } else {                    // layer3: 4 z * 256 row-groups
        bid -= 256;
        int z = bid >> 8, bx = bid & 255;
        prep_body<256>(gen3, tar3, gnT3, tnT3, 4096, z, bx, smem);
    }
}

// ===== gemm (R14 core; epilogue writes paired ushort8 in the 16B layout) =====
template <int K>
__device__ __forceinline__ void gemm_body(
    const ushort_t* __restrict__ A, const ushort_t* __restrict__ B,
    ushort_t* __restrict__ sim, float* __restrict__ cmPart,
    int S, int bx, int by, ushort_t* __restrict__ lds) {
    const int tid = threadIdx.x;
    const int lane = tid & 63, wave = tid >> 6;
    const int wm = (wave & 1) * 64, wn = (wave >> 1) * 64;
    const int lm = lane & 15, quad = lane >> 4;
    const int q0 = bx * 128;

    constexpr int KC = K / 8;
    constexpr int KB = K / 32;

    const ushort_t* segsrc[4];
    ushort_t* segdst[4];
#pragma unroll
    for (int i = 0; i < 4; i++) {
        int s = wave * 4 + i;
        segsrc[i] = (s < 8)
            ? A + ((size_t)(by * 8 + s) * KC) * 128 + lane * 8
            : B + ((size_t)(bx * 8 + (s - 8)) * KC) * 128 + lane * 8;
        segdst[i] = lds + s * 512;
    }

    auto stage = [&](int buf, int kb) {
#pragma unroll
        for (int i = 0; i < 4; i++)
            gload16(segsrc[i] + (size_t)kb * 512, segdst[i] + buf * 8192);
    };

    f32x4 acc[4][4];
#pragma unroll
    for (int t = 0; t < 4; t++)
#pragma unroll
        for (int u = 0; u < 4; u++) acc[t][u] = (f32x4){0.f, 0.f, 0.f, 0.f};

    stage(0, 0);
    stage(1, 1);
    asm volatile("s_waitcnt vmcnt(4)" ::: "memory");
    __builtin_amdgcn_s_barrier();
    __builtin_amdgcn_sched_barrier(0);

    const ushort_t* lA = lds + (wm >> 4) * 512 + quad * 128 + lm * 8;
    const ushort_t* lB = lds + 4096 + (wn >> 4) * 512 + quad * 128 + lm * 8;

#pragma unroll
    for (int kb = 0; kb < KB; kb++) {
        const int cur = (kb % 3) * 8192;
        if (kb + 2 < KB) stage((kb + 2) % 3, kb + 2);
        bf16x8 a[4], b[4];
#pragma unroll
        for (int t = 0; t < 4; t++) {
            a[t] = *(const bf16x8*)(lA + cur + t * 512);
            b[t] = *(const bf16x8*)(lB + cur + t * 512);
        }
        __builtin_amdgcn_s_setprio(1);
#pragma unroll
        for (int t = 0; t < 4; t++)
#pragma unroll
            for (int u = 0; u < 4; u++)
                acc[t][u] = __builtin_amdgcn_mfma_f32_16x16x32_bf16(a[t], b[u], acc[t][u], 0, 0, 0);
        __builtin_amdgcn_s_setprio(0);
        if (kb + 1 < KB) {
            if (kb + 2 < KB) asm volatile("s_waitcnt vmcnt(4)" ::: "memory");
            else             asm volatile("s_waitcnt vmcnt(0)" ::: "memory");
            __builtin_amdgcn_s_barrier();
            __builtin_amdgcn_sched_barrier(0);
        }
    }

    int nQB = S >> 7;
    size_t base = ((size_t)(by * nQB + bx)) * 16384
                + (size_t)(wave * 4096 + quad * 128 + lm * 8);
    float cmax[4] = {-INFINITY, -INFINITY, -INFINITY, -INFINITY};
#pragma unroll
    for (int t2 = 0; t2 < 2; t2++)
#pragma unroll
        for (int u = 0; u < 4; u++) {
            f32x4 v0 = acc[t2 * 2][u], v1 = acc[t2 * 2 + 1][u];
            ushort8_t o;
            o.v[0] = f2bf(v0.x); o.v[1] = f2bf(v0.y); o.v[2] = f2bf(v0.z); o.v[3] = f2bf(v0.w);
            o.v[4] = f2bf(v1.x); o.v[5] = f2bf(v1.y); o.v[6] = f2bf(v1.z); o.v[7] = f2bf(v1.w);
            *(ushort8_t*)(sim + base + (t2 * 4 + u) * 512) = o;
            float mx = fmaxf(fmaxf(fmaxf(bf2f(o.v[0]), bf2f(o.v[1])), fmaxf(bf2f(o.v[2]), bf2f(o.v[3]))),
                             fmaxf(fmaxf(bf2f(o.v[4]), bf2f(o.v[5])), fmaxf(bf2f(o.v[6]), bf2f(o.v[7]))));
            cmax[u] = fmaxf(cmax[u], mx);
        }
    int r = by * 2 + (wave & 1);
#pragma unroll
    for (int u = 0; u < 4; u++) {
        float m = cmax[u];
        m = fmaxf(m, __shfl_xor(m, 16, 64));
        m = fmaxf(m, __shfl_xor(m, 32, 64));
        if (lane < 16) cmPart[(size_t)r * S + q0 + wn + u * 16 + lane] = m;
    }
}

__global__ __launch_bounds__(256) void gemm_all(
    const ushort_t* __restrict__ tnT3, const ushort_t* __restrict__ gnT3,
    ushort_t* __restrict__ sim3, float* __restrict__ cmPart3,
    const ushort_t* __restrict__ tnT4, const ushort_t* __restrict__ gnT4,
    ushort_t* __restrict__ sim4, float* __restrict__ cmPart4) {
    __shared__ ushort_t lds[24576];   // 3 bufs x (A 8KB + B 8KB) = 48 KB
    // Balanced per-layer XCD chunking (grid 4352 = 8 XCD x 544):
    // each XCD: 32 layer4 blocks (heavy, first) + 512 consecutive layer3 bids
    // (contiguous by-panels -> A-panel/B L2 reuse). Bijective partition.
    int xcd = blockIdx.x & 7, j = blockIdx.x >> 3;
    int bid = (j < 32) ? (xcd * 32 + j) : (256 + xcd * 512 + (j - 32));
    if (bid < 256) {            // layer4 (2x K per block)
        int z = bid >> 6, rem = bid & 63, by = rem >> 3, bx = rem & 7;
        gemm_body<512>(tnT4 + (size_t)z * 524288, gnT4 + (size_t)z * 524288,
                       sim4 + (size_t)z * 1048576, cmPart4 + (size_t)z * 16384,
                       1024, bx, by, lds);
    } else {
        bid -= 256;
        int z = bid >> 10, rem = bid & 1023, by = rem >> 5, bx = rem & 31;
        gemm_body<256>(tnT3 + (size_t)z * 1048576, gnT3 + (size_t)z * 1048576,
                       sim3 + (size_t)z * 16777216, cmPart3 + (size_t)z * 262144,
                       4096, bx, by, lds);
    }
}

// ================= colmax reduce -> coef, zero colsum + acc =================
__global__ __launch_bounds__(256) void colmax_reduce_all(
    const float* __restrict__ cmPart3, float2* __restrict__ coef3, float* __restrict__ colsum3,
    const float* __restrict__ cmPart4, float2* __restrict__ coef4, float* __restrict__ colsum4,
    float* __restrict__ acc) {
    const float* cmPart; float2* coef; float* colsum; int S, R, qb, accIdx;
    int bid = blockIdx.x;
    if (bid < 16) {             // layer4: 4 z * 4 blocks
        int z = bid >> 2; qb = bid & 3; S = 1024; R = 16; accIdx = 4 + z;
        cmPart = cmPart4 + (size_t)z * 16384; coef = coef4 + (size_t)z * 1024;
        colsum = colsum4 + (size_t)z * 1024;
    } else {
        bid -= 16;
        int z = bid >> 4; qb = bid & 15; S = 4096; R = 64; accIdx = z;
        cmPart = cmPart3 + (size_t)z * 262144; coef = coef3 + (size_t)z * 4096;
        colsum = colsum3 + (size_t)z * 4096;
    }
    if (qb == 0 && threadIdx.x == 0) acc[accIdx] = 0.f;
    int q = qb * 256 + threadIdx.x;
    float m = cmPart[q];
    for (int r = 1; r < R; r++) m = fmaxf(m, cmPart[(size_t)r * S + q]);
    float c1 = 1.f / ((1.f - m) * 0.5f + MRF_EPS);
    coef[q] = make_float2((2.f - c1) * LOG2E, c1 * LOG2E);
    colsum[q] = 0.f;
}

// ================= colsum (16B reads, 1KB/wave) =================
__global__ __launch_bounds__(256) void colsum_all(
    const ushort_t* __restrict__ sim3, const float2* __restrict__ coef3, float* __restrict__ colsum3,
    const ushort_t* __restrict__ sim4, const float2* __restrict__ coef4, float* __restrict__ colsum4) {
    const ushort_t* sim; const float2* coef; float* colsum; int S, bx, by;
    int bid = blockIdx.x;
    if (bid < 256) {            // layer4: 4 z * (8 x 8)
        int z = bid >> 6, rem = bid & 63; by = rem >> 3; bx = rem & 7; S = 1024;
        sim = sim4 + (size_t)z * 1048576; coef = coef4 + (size_t)z * 1024;
        colsum = colsum4 + (size_t)z * 1024;
    } else {
        bid -= 256;
        int z = bid >> 10, rem = bid & 1023; by = rem >> 5; bx = rem & 31; S = 4096;
        sim = sim3 + (size_t)z * 16777216; coef = coef3 + (size_t)z * 4096;
        colsum = colsum3 + (size_t)z * 4096;
    }
    int tid = threadIdx.x, lane = tid & 63;
    int quad = lane >> 4, lm = lane & 15;
    int sub = (tid >> 6) & 1, cg = tid >> 7;
    int slot = sub | (cg << 1);
    int nQB = S >> 7;
    int qb = bx * 128 + cg * 64 + lm;
    float c0[4], c1[4], su[4];
#pragma unroll
    for (int u = 0; u < 4; u++) {
        float2 cc = coef[qb + u * 16];
        c0[u] = cc.x; c1[u] = cc.y; su[u] = 0.f;
    }
    const ushort_t* base = sim + ((size_t)(by * nQB + bx)) * 16384
                         + (size_t)(slot * 4096 + quad * 128 + lm * 8);
#pragma unroll
    for (int t2 = 0; t2 < 2; t2++)
#pragma unroll
        for (int u = 0; u < 4; u++) {
            ushort8_t e = *(const ushort8_t*)(base + (t2 * 4 + u) * 512);
            float s = 0.f;
#pragma unroll
            for (int j = 0; j < 8; j++) s += exp2f(c0[u] + c1[u] * bf2f(e.v[j]));
            su[u] += s;
        }
#pragma unroll
    for (int u = 0; u < 4; u++) {
        su[u] += __shfl_xor(su[u], 16, 64);
        su[u] += __shfl_xor(su[u], 32, 64);
        if (lane < 16) atomicAdd(colsum + qb + u * 16, su[u]);
    }
}

// ======= rowmax (16B reads, 1KB/wave; G-split bx, partials -> rmPart) =======
template <int NQB, int NBX>
__device__ __forceinline__ void rowmax_body(
    const ushort_t* __restrict__ sim, const float2* __restrict__ coef,
    const float* __restrict__ colsum, float* __restrict__ rmPart,
    int by, int g) {
    int tid = threadIdx.x, lane = tid & 63, wave = tid >> 6;
    int ph = wave & 1, t2 = wave >> 1;
    int quad = lane >> 4, lm = lane & 15;
    float m[8];
#pragma unroll
    for (int j = 0; j < 8; j++) m[j] = -INFINITY;
    for (int bxi = 0; bxi < NBX; bxi++) {
        int bx = g * NBX + bxi;
        float c0p[8], c1v[8];
#pragma unroll
        for (int cg = 0; cg < 2; cg++)
#pragma unroll
            for (int u = 0; u < 4; u++) {
                int q = bx * 128 + cg * 64 + u * 16 + lm;
                float2 cc = coef[q];
                c0p[cg * 4 + u] = cc.x - log2f(colsum[q]);
                c1v[cg * 4 + u] = cc.y;
            }
        const ushort_t* bb = sim + ((size_t)(by * NQB + bx)) * 16384
                           + (size_t)((t2 * 4) * 512 + quad * 128 + lm * 8);
#pragma unroll
        for (int cg = 0; cg < 2; cg++) {
            int slot = ph + 2 * cg;
#pragma unroll
            for (int u = 0; u < 4; u++) {
                ushort8_t e = *(const ushort8_t*)(bb + slot * 4096 + u * 512);
                float a = c0p[cg * 4 + u], c = c1v[cg * 4 + u];
#pragma unroll
                for (int j = 0; j < 8; j++) m[j] = fmaxf(m[j], a + c * bf2f(e.v[j]));
            }
        }
    }
    // reduce over the 16 lm lanes (they share the same p-set)
#pragma unroll
    for (int off = 1; off <= 8; off <<= 1)
#pragma unroll
        for (int j = 0; j < 8; j++) m[j] = fmaxf(m[j], __shfl_xor(m[j], off, 64));
    if (lm == 0) {
        int pbase = by * 128 + ph * 64 + t2 * 32 + quad * 4;
#pragma unroll
        for (int j = 0; j < 8; j++)
            rmPart[pbase + (j >> 2) * 16 + (j & 3)] = m[j];
    }
}

__global__ __launch_bounds__(256) void rowmax_all(
    const ushort_t* __restrict__ sim3, const float2* __restrict__ coef3, const float* __restrict__ colsum3,
    float* __restrict__ rmPart3,
    const ushort_t* __restrict__ sim4, const float2* __restrict__ coef4, const float* __restrict__ colsum4,
    float* __restrict__ rmPart4) {
    int bid = blockIdx.x;
    if (bid < 1024) {           // layer3: 4z * 32by * 8g
        int z = bid >> 8, rem = bid & 255, by = rem >> 3, g = rem & 7;
        rowmax_body<32, 4>(sim3 + (size_t)z * 16777216, coef3 + (size_t)z * 4096,
                           colsum3 + (size_t)z * 4096,
                           rmPart3 + ((size_t)(z * 8 + g)) * 4096, by, g);
    } else {                    // layer4: 4z * 8by * 4g
        bid -= 1024;
        int z = bid >> 5, rem = bid & 31, by = rem >> 2, g = rem & 3;
        rowmax_body<8, 2>(sim4 + (size_t)z * 1048576, coef4 + (size_t)z * 1024,
                          colsum4 + (size_t)z * 1024,
                          rmPart4 + ((size_t)(z * 4 + g)) * 1024, by, g);
    }
}

// ===== rowmax partial reduce -> exp2 -> acc =====
__global__ __launch_bounds__(256) void rmreduce_all(
    const float* __restrict__ rmPart3, const float* __restrict__ rmPart4,
    float* __restrict__ acc) {
    const float* rm; int G, stride, p; float* slot;
    int bid = blockIdx.x;
    if (bid < 64) {             // layer3: 4z * 16 blocks
        int z = bid >> 4, blk = bid & 15; G = 8; stride = 4096;
        rm = rmPart3 + (size_t)z * 8 * 4096;
        p = blk * 256 + threadIdx.x; slot = acc + z;
    } else {
        bid -= 64;              // layer4: 4z * 4 blocks
        int z = bid >> 2, blk = bid & 3; G = 4; stride = 1024;
        rm = rmPart4 + (size_t)z * 4 * 1024;
        p = blk * 256 + threadIdx.x; slot = acc + 4 + z;
    }
    float m = rm[p];
    for (int g = 1; g < G; g++) m = fmaxf(m, rm[(size_t)g * stride + p]);
    float k = exp2f(m);
#pragma unroll
    for (int off = 32; off >= 1; off >>= 1) k += __shfl_xor(k, off, 64);
    __shared__ float part[4];
    if ((threadIdx.x & 63) == 0) part[threadIdx.x >> 6] = k;
    __syncthreads();
    if (threadIdx.x == 0)
        atomicAdd(slot, part[0] + part[1] + part[2] + part[3]);
}

__global__ void finalize_kernel(const float* __restrict__ acc, float* __restrict__ out) {
    float loss = 0.f;
    for (int b = 0; b < 4; b++) loss += -logf(acc[b] * (1.f / 4096.f));
    for (int b = 0; b < 4; b++) loss += -2.f * logf(acc[4 + b] * (1.f / 1024.f));
    out[0] = loss;
}

extern "C" void kernel_launch(void* const* d_in, const int* in_sizes, int n_in,
                              void* d_out, int out_size, void* d_ws, size_t ws_size,
                              hipStream_t stream) {
    const float* gen3 = (const float*)d_in[0];
    const float* tar3 = (const float*)d_in[1];
    const float* gen4 = (const float*)d_in[2];
    const float* tar4 = (const float*)d_in[3];

    char* wsb = (char*)d_ws;
    size_t off = 0;
    auto alloc = [&](size_t bytes) {
        void* p = wsb + off;
        off += (bytes + 255) & ~(size_t)255;
        return p;
    };
    // layer3 (z=4): S=4096, C=256, R=64, nQB=32
    ushort_t* sim3 = (ushort_t*)alloc((size_t)4 * 16777216 * 2);   // 134.2 MB
    ushort_t* gnT3 = (ushort_t*)alloc((size_t)4 * 1048576 * 2);    // 8.4 MB
    ushort_t* tnT3 = (ushort_t*)alloc((size_t)4 * 1048576 * 2);    // 8.4 MB
    float* cmPart3 = (float*)alloc((size_t)4 * 262144 * 4);        // 4.2 MB
    float2* coef3 = (float2*)alloc((size_t)4 * 4096 * 8);
    float* colsum3 = (float*)alloc((size_t)4 * 4096 * 4);
    float* rmPart3 = (float*)alloc((size_t)4 * 8 * 4096 * 4);      // 512 KB
    // layer4 (z=4): S=1024, C=512, R=16, nQB=8
    ushort_t* sim4 = (ushort_t*)alloc((size_t)4 * 1048576 * 2);    // 8.4 MB
    ushort_t* gnT4 = (ushort_t*)alloc((size_t)4 * 524288 * 2);     // 4.2 MB
    ushort_t* tnT4 = (ushort_t*)alloc((size_t)4 * 524288 * 2);     // 4.2 MB
    float* cmPart4 = (float*)alloc((size_t)4 * 16384 * 4);
    float2* coef4 = (float2*)alloc((size_t)4 * 1024 * 8);
    float* colsum4 = (float*)alloc((size_t)4 * 1024 * 4);
    float* rmPart4 = (float*)alloc((size_t)4 * 4 * 1024 * 4);
    float* acc = (float*)alloc(64 * 4);
    // total ~173 MB (ws is 256 MiB)

    prep_all<<<256 + 1024, 256, 0, stream>>>(
        gen3, tar3, gen4, tar4, gnT3, tnT3, gnT4, tnT4);
    gemm_all<<<256 + 4096, 256, 0, stream>>>(
        tnT3, gnT3, sim3, cmPart3, tnT4, gnT4, sim4, cmPart4);
    colmax_reduce_all<<<16 + 64, 256, 0, stream>>>(
        cmPart3, coef3, colsum3, cmPart4, coef4, colsum4, acc);
    colsum_all<<<256 + 4096, 256, 0, stream>>>(
        sim3, coef3, colsum3, sim4, coef4, colsum4);
    rowmax_all<<<1024 + 128, 256, 0, stream>>>(
        sim3, coef3, colsum3, rmPart3, sim4, coef4, colsum4, rmPart4);
    rmreduce_all<<<64 + 16, 256, 0, stream>>>(rmPart3, rmPart4, acc);
    finalize_kernel<<<1, 1, 0, stream>>>(acc, (float*)d_out);
}

// Round 8
// 215.979 us; speedup vs baseline: 1.0223x; 1.0203x over previous
//
#include <hip/hip_runtime.h>
#include <math.h>

// IDMRFLoss on MI355X — R19: single-variable isolation. R18 showed balanced
// XCD chunking did NOT restore gemm (67us vs R16-identity's 52us); both
// non-identity orders (R17 bad swizzle, R18 balanced chunks) cost ~15us.
// Hypothesis: real workgroup->XCD mapping != blockIdx%8, so any remap
// scatters the natural neighbor-block locality identity order gets free.
// R19 = R18 with gemm dispatch reverted to IDENTITY; 16B sim layout kept
// (colsum+rowmax ~11us gain, proven R16->R17). All else byte-identical.
//
// sim per-128x128-block layout (16B-granular):
//   elem = slot*4096 + (t2*4+u)*512 + quad*128 + lm*8 + th*4 + r  (t=2*t2+th)
//   p = by*128+(slot&1)*64+t2*32+th*16+quad*4+r ; q = bx*128+(slot>>1)*64+u*16+lm
// Swizzled operand layout (per batch, matrix [S][K] bf16):
//   elem(row,k) at ((row>>4)*(K/8) + (k>>3))*128 + (row&15)*8 + (k&7)
//
// Math (per combo): c1 = 1/((1-colmax)/2+eps); log2 domain c1L=c1*log2e,
// c0L=(2-c1)*log2e; colsum_q = sum_p 2^(c0L+c1L*v);
// kmax_p = 2^(max_q (c0L - log2(colsum_q) + c1L*v)); loss = sum -w*log(mean kmax).

#define MRF_EPS 1e-5f
#define LOG2E 1.44269504088896340736f

typedef __attribute__((ext_vector_type(8))) short bf16x8;
typedef __attribute__((ext_vector_type(4))) float f32x4;
typedef unsigned short ushort_t;
struct __align__(8) ushort4_t { ushort_t x, y, z, w; };
struct __align__(16) ushort8_t { ushort_t v[8]; };

__device__ __forceinline__ ushort_t f2bf(float x) {
    unsigned u = __float_as_uint(x);
    u += 0x7FFFu + ((u >> 16) & 1u);
    return (ushort_t)(u >> 16);
}
__device__ __forceinline__ float bf2f(ushort_t u) {
    return __uint_as_float(((unsigned)u) << 16);
}

// async global->LDS, 16B per lane. LDS dest is wave-uniform base + lane*16.
typedef __attribute__((address_space(1))) const unsigned int gu32;
typedef __attribute__((address_space(3))) unsigned int lu32;
__device__ __forceinline__ void gload16(const ushort_t* g, ushort_t* l) {
    __builtin_amdgcn_global_load_lds((gu32*)(uintptr_t)g, (lu32*)(uintptr_t)l,
                                     16, 0, 0);
}

// ===== prep: fused stats+apply (one input pass, data held in registers) =====
template <int C>
__device__ __forceinline__ void prep_body(
    const float* __restrict__ gen, const float* __restrict__ tar,
    ushort_t* __restrict__ gnT, ushort_t* __restrict__ tnT,
    int S, int b, int bx, char* __restrict__ smem) {
    constexpr int KN = C / 64;   // f32x4 loads per thread per tensor
    constexpr int KC = C / 8;    // swizzle chunks
    constexpr int CP = C + 8;    // padded LDS tile stride (elems)
    const int tid = threadIdx.x, pq = tid & 3, cs = tid >> 2;
    const int s0 = bx * 16;

    f32x4* red  = (f32x4*)smem;            // [4][4][64], 16 KB (dead after stats)
    f32x4* red2 = (f32x4*)(smem + 16384);  // [4][4][4]
    ushort_t* tileG = (ushort_t*)smem;     // [16][CP] bf16 — aliases red region
    ushort_t* tileT = tileG + 16 * CP;
    float* sm  = (float*)(smem + 33280);   // [16] mean (beyond tile region)
    float* srt = sm + 16;                  // [16] rsqrt var_t
    float* srg = sm + 32;                  // [16] rsqrt var_g

    const float* g = gen + (size_t)b * C * S + s0 + pq * 4;
    const float* t = tar + (size_t)b * C * S + s0 + pq * 4;

    f32x4 gv[KN], tv[KN];
    f32x4 st = {0.f, 0.f, 0.f, 0.f}, st2 = st, sg = st, sg2 = st;
#pragma unroll
    for (int k = 0; k < KN; k++) {          // c = cs + 64k, ascending (== old order)
        tv[k] = *(const f32x4*)(t + (size_t)(cs + 64 * k) * S);
        gv[k] = *(const f32x4*)(g + (size_t)(cs + 64 * k) * S);
        st += tv[k]; st2 += tv[k] * tv[k]; sg += gv[k]; sg2 += gv[k] * gv[k];
    }
    red[(0 * 4 + pq) * 64 + cs] = st;  red[(1 * 4 + pq) * 64 + cs] = st2;
    red[(2 * 4 + pq) * 64 + cs] = sg;  red[(3 * 4 + pq) * 64 + cs] = sg2;
    __syncthreads();
    if (tid < 64) {
        int s_ = tid >> 4, p_ = (tid >> 2) & 3, part = tid & 3;
        f32x4 s = red[(s_ * 4 + p_) * 64 + part * 16];
#pragma unroll
        for (int j = 1; j < 16; j++) s += red[(s_ * 4 + p_) * 64 + part * 16 + j];
        red2[(s_ * 4 + p_) * 4 + part] = s;
    }
    __syncthreads();
    if (tid < 4) {
        f32x4 sts  = red2[(0*4+tid)*4+0] + red2[(0*4+tid)*4+1] + red2[(0*4+tid)*4+2] + red2[(0*4+tid)*4+3];
        f32x4 st2s = red2[(1*4+tid)*4+0] + red2[(1*4+tid)*4+1] + red2[(1*4+tid)*4+2] + red2[(1*4+tid)*4+3];
        f32x4 sgs  = red2[(2*4+tid)*4+0] + red2[(2*4+tid)*4+1] + red2[(2*4+tid)*4+2] + red2[(2*4+tid)*4+3];
        f32x4 sg2s = red2[(3*4+tid)*4+0] + red2[(3*4+tid)*4+1] + red2[(3*4+tid)*4+2] + red2[(3*4+tid)*4+3];
        f32x4 m, vrt, vrg;
        float invC = 1.f / (float)C;
#pragma unroll
        for (int e = 0; e < 4; e++) {
            float mm = sts[e] * invC;
            m[e] = mm;
            vrt[e] = rsqrtf(st2s[e] - mm * sts[e]);
            vrg[e] = rsqrtf(sg2s[e] - 2.f * mm * sgs[e] + mm * sts[e]);
        }
        *(f32x4*)&sm[tid * 4] = m;
        *(f32x4*)&srt[tid * 4] = vrt;
        *(f32x4*)&srg[tid * 4] = vrg;
    }
    __syncthreads();   // red/red2 dead; tile region may now be written
    f32x4 m4  = *(f32x4*)&sm[pq * 4];
    f32x4 rt4 = *(f32x4*)&srt[pq * 4];
    f32x4 rg4 = *(f32x4*)&srg[pq * 4];
#pragma unroll
    for (int k = 0; k < KN; k++) {
        int c = cs + 64 * k;
#pragma unroll
        for (int e = 0; e < 4; e++) {
            tileG[(pq * 4 + e) * CP + c] = f2bf((gv[k][e] - m4[e]) * rg4[e]);
            tileT[(pq * 4 + e) * CP + c] = f2bf((tv[k][e] - m4[e]) * rt4[e]);
        }
    }
    __syncthreads();
    const int lm = tid & 15;
    const int r16 = s0 >> 4;
    size_t obase = (size_t)b * (size_t)S * C;
#pragma unroll
    for (int j = 0; j < KC / 16; j++) {
        int ch = (tid >> 4) + 16 * j;
        size_t off = obase + (((size_t)r16 * KC + ch) * 16 + lm) * 8;
        *(ushort8_t*)(gnT + off) = *(const ushort8_t*)&tileG[lm * CP + ch * 8];
        *(ushort8_t*)(tnT + off) = *(const ushort8_t*)&tileT[lm * CP + ch * 8];
    }
}

__global__ __launch_bounds__(256) void prep_all(
    const float* __restrict__ gen3, const float* __restrict__ tar3,
    const float* __restrict__ gen4, const float* __restrict__ tar4,
    ushort_t* __restrict__ gnT3, ushort_t* __restrict__ tnT3,
    ushort_t* __restrict__ gnT4, ushort_t* __restrict__ tnT4) {
    __shared__ __align__(16) char smem[33536];
    int bid = blockIdx.x;        // identity
    if (bid < 256) {            // layer4: 4 z * 64 row-groups
        int z = bid >> 6, bx = bid & 63;
        prep_body<512>(gen4, tar4, gnT4, tnT4, 1024, z, bx, smem);
    } else {                    // layer3: 4 z * 256 row-groups
        bid -= 256;
        int z = bid >> 8, bx = bid & 255;
        prep_body<256>(gen3, tar3, gnT3, tnT3, 4096, z, bx, smem);
    }
}

// ===== gemm (R14 core; epilogue writes paired ushort8 in the 16B layout) =====
template <int K>
__device__ __forceinline__ void gemm_body(
    const ushort_t* __restrict__ A, const ushort_t* __restrict__ B,
    ushort_t* __restrict__ sim, float* __restrict__ cmPart,
    int S, int bx, int by, ushort_t* __restrict__ lds) {
    const int tid = threadIdx.x;
    const int lane = tid & 63, wave = tid >> 6;
    const int wm = (wave & 1) * 64, wn = (wave >> 1) * 64;
    const int lm = lane & 15, quad = lane >> 4;
    const int q0 = bx * 128;

    constexpr int KC = K / 8;
    constexpr int KB = K / 32;

    const ushort_t* segsrc[4];
    ushort_t* segdst[4];
#pragma unroll
    for (int i = 0; i < 4; i++) {
        int s = wave * 4 + i;
        segsrc[i] = (s < 8)
            ? A + ((size_t)(by * 8 + s) * KC) * 128 + lane * 8
            : B + ((size_t)(bx * 8 + (s - 8)) * KC) * 128 + lane * 8;
        segdst[i] = lds + s * 512;
    }

    auto stage = [&](int buf, int kb) {
#pragma unroll
        for (int i = 0; i < 4; i++)
            gload16(segsrc[i] + (size_t)kb * 512, segdst[i] + buf * 8192);
    };

    f32x4 acc[4][4];
#pragma unroll
    for (int t = 0; t < 4; t++)
#pragma unroll
        for (int u = 0; u < 4; u++) acc[t][u] = (f32x4){0.f, 0.f, 0.f, 0.f};

    stage(0, 0);
    stage(1, 1);
    asm volatile("s_waitcnt vmcnt(4)" ::: "memory");
    __builtin_amdgcn_s_barrier();
    __builtin_amdgcn_sched_barrier(0);

    const ushort_t* lA = lds + (wm >> 4) * 512 + quad * 128 + lm * 8;
    const ushort_t* lB = lds + 4096 + (wn >> 4) * 512 + quad * 128 + lm * 8;

#pragma unroll
    for (int kb = 0; kb < KB; kb++) {
        const int cur = (kb % 3) * 8192;
        if (kb + 2 < KB) stage((kb + 2) % 3, kb + 2);
        bf16x8 a[4], b[4];
#pragma unroll
        for (int t = 0; t < 4; t++) {
            a[t] = *(const bf16x8*)(lA + cur + t * 512);
            b[t] = *(const bf16x8*)(lB + cur + t * 512);
        }
        __builtin_amdgcn_s_setprio(1);
#pragma unroll
        for (int t = 0; t < 4; t++)
#pragma unroll
            for (int u = 0; u < 4; u++)
                acc[t][u] = __builtin_amdgcn_mfma_f32_16x16x32_bf16(a[t], b[u], acc[t][u], 0, 0, 0);
        __builtin_amdgcn_s_setprio(0);
        if (kb + 1 < KB) {
            if (kb + 2 < KB) asm volatile("s_waitcnt vmcnt(4)" ::: "memory");
            else             asm volatile("s_waitcnt vmcnt(0)" ::: "memory");
            __builtin_amdgcn_s_barrier();
            __builtin_amdgcn_sched_barrier(0);
        }
    }

    int nQB = S >> 7;
    size_t base = ((size_t)(by * nQB + bx)) * 16384
                + (size_t)(wave * 4096 + quad * 128 + lm * 8);
    float cmax[4] = {-INFINITY, -INFINITY, -INFINITY, -INFINITY};
#pragma unroll
    for (int t2 = 0; t2 < 2; t2++)
#pragma unroll
        for (int u = 0; u < 4; u++) {
            f32x4 v0 = acc[t2 * 2][u], v1 = acc[t2 * 2 + 1][u];
            ushort8_t o;
            o.v[0] = f2bf(v0.x); o.v[1] = f2bf(v0.y); o.v[2] = f2bf(v0.z); o.v[3] = f2bf(v0.w);
            o.v[4] = f2bf(v1.x); o.v[5] = f2bf(v1.y); o.v[6] = f2bf(v1.z); o.v[7] = f2bf(v1.w);
            *(ushort8_t*)(sim + base + (t2 * 4 + u) * 512) = o;
            float mx = fmaxf(fmaxf(fmaxf(bf2f(o.v[0]), bf2f(o.v[1])), fmaxf(bf2f(o.v[2]), bf2f(o.v[3]))),
                             fmaxf(fmaxf(bf2f(o.v[4]), bf2f(o.v[5])), fmaxf(bf2f(o.v[6]), bf2f(o.v[7]))));
            cmax[u] = fmaxf(cmax[u], mx);
        }
    int r = by * 2 + (wave & 1);
#pragma unroll
    for (int u = 0; u < 4; u++) {
        float m = cmax[u];
        m = fmaxf(m, __shfl_xor(m, 16, 64));
        m = fmaxf(m, __shfl_xor(m, 32, 64));
        if (lane < 16) cmPart[(size_t)r * S + q0 + wn + u * 16 + lane] = m;
    }
}

__global__ __launch_bounds__(256) void gemm_all(
    const ushort_t* __restrict__ tnT3, const ushort_t* __restrict__ gnT3,
    ushort_t* __restrict__ sim3, float* __restrict__ cmPart3,
    const ushort_t* __restrict__ tnT4, const ushort_t* __restrict__ gnT4,
    ushort_t* __restrict__ sim4, float* __restrict__ cmPart4) {
    __shared__ ushort_t lds[24576];   // 3 bufs x (A 8KB + B 8KB) = 48 KB
    int bid = blockIdx.x;        // identity (R16-proven; any remap cost ~15us)
    if (bid < 256) {            // layer4 first (2x K per block)
        int z = bid >> 6, rem = bid & 63, by = rem >> 3, bx = rem & 7;
        gemm_body<512>(tnT4 + (size_t)z * 524288, gnT4 + (size_t)z * 524288,
                       sim4 + (size_t)z * 1048576, cmPart4 + (size_t)z * 16384,
                       1024, bx, by, lds);
    } else {
        bid -= 256;
        int z = bid >> 10, rem = bid & 1023, by = rem >> 5, bx = rem & 31;
        gemm_body<256>(tnT3 + (size_t)z * 1048576, gnT3 + (size_t)z * 1048576,
                       sim3 + (size_t)z * 16777216, cmPart3 + (size_t)z * 262144,
                       4096, bx, by, lds);
    }
}

// ================= colmax reduce -> coef, zero colsum + acc =================
__global__ __launch_bounds__(256) void colmax_reduce_all(
    const float* __restrict__ cmPart3, float2* __restrict__ coef3, float* __restrict__ colsum3,
    const float* __restrict__ cmPart4, float2* __restrict__ coef4, float* __restrict__ colsum4,
    float* __restrict__ acc) {
    const float* cmPart; float2* coef; float* colsum; int S, R, qb, accIdx;
    int bid = blockIdx.x;
    if (bid < 16) {             // layer4: 4 z * 4 blocks
        int z = bid >> 2; qb = bid & 3; S = 1024; R = 16; accIdx = 4 + z;
        cmPart = cmPart4 + (size_t)z * 16384; coef = coef4 + (size_t)z * 1024;
        colsum = colsum4 + (size_t)z * 1024;
    } else {
        bid -= 16;
        int z = bid >> 4; qb = bid & 15; S = 4096; R = 64; accIdx = z;
        cmPart = cmPart3 + (size_t)z * 262144; coef = coef3 + (size_t)z * 4096;
        colsum = colsum3 + (size_t)z * 4096;
    }
    if (qb == 0 && threadIdx.x == 0) acc[accIdx] = 0.f;
    int q = qb * 256 + threadIdx.x;
    float m = cmPart[q];
    for (int r = 1; r < R; r++) m = fmaxf(m, cmPart[(size_t)r * S + q]);
    float c1 = 1.f / ((1.f - m) * 0.5f + MRF_EPS);
    coef[q] = make_float2((2.f - c1) * LOG2E, c1 * LOG2E);
    colsum[q] = 0.f;
}

// ================= colsum (16B reads, 1KB/wave) =================
__global__ __launch_bounds__(256) void colsum_all(
    const ushort_t* __restrict__ sim3, const float2* __restrict__ coef3, float* __restrict__ colsum3,
    const ushort_t* __restrict__ sim4, const float2* __restrict__ coef4, float* __restrict__ colsum4) {
    const ushort_t* sim; const float2* coef; float* colsum; int S, bx, by;
    int bid = blockIdx.x;
    if (bid < 256) {            // layer4: 4 z * (8 x 8)
        int z = bid >> 6, rem = bid & 63; by = rem >> 3; bx = rem & 7; S = 1024;
        sim = sim4 + (size_t)z * 1048576; coef = coef4 + (size_t)z * 1024;
        colsum = colsum4 + (size_t)z * 1024;
    } else {
        bid -= 256;
        int z = bid >> 10, rem = bid & 1023; by = rem >> 5; bx = rem & 31; S = 4096;
        sim = sim3 + (size_t)z * 16777216; coef = coef3 + (size_t)z * 4096;
        colsum = colsum3 + (size_t)z * 4096;
    }
    int tid = threadIdx.x, lane = tid & 63;
    int quad = lane >> 4, lm = lane & 15;
    int sub = (tid >> 6) & 1, cg = tid >> 7;
    int slot = sub | (cg << 1);
    int nQB = S >> 7;
    int qb = bx * 128 + cg * 64 + lm;
    float c0[4], c1[4], su[4];
#pragma unroll
    for (int u = 0; u < 4; u++) {
        float2 cc = coef[qb + u * 16];
        c0[u] = cc.x; c1[u] = cc.y; su[u] = 0.f;
    }
    const ushort_t* base = sim + ((size_t)(by * nQB + bx)) * 16384
                         + (size_t)(slot * 4096 + quad * 128 + lm * 8);
#pragma unroll
    for (int t2 = 0; t2 < 2; t2++)
#pragma unroll
        for (int u = 0; u < 4; u++) {
            ushort8_t e = *(const ushort8_t*)(base + (t2 * 4 + u) * 512);
            float s = 0.f;
#pragma unroll
            for (int j = 0; j < 8; j++) s += exp2f(c0[u] + c1[u] * bf2f(e.v[j]));
            su[u] += s;
        }
#pragma unroll
    for (int u = 0; u < 4; u++) {
        su[u] += __shfl_xor(su[u], 16, 64);
        su[u] += __shfl_xor(su[u], 32, 64);
        if (lane < 16) atomicAdd(colsum + qb + u * 16, su[u]);
    }
}

// ======= rowmax (16B reads, 1KB/wave; G-split bx, partials -> rmPart) =======
template <int NQB, int NBX>
__device__ __forceinline__ void rowmax_body(
    const ushort_t* __restrict__ sim, const float2* __restrict__ coef,
    const float* __restrict__ colsum, float* __restrict__ rmPart,
    int by, int g) {
    int tid = threadIdx.x, lane = tid & 63, wave = tid >> 6;
    int ph = wave & 1, t2 = wave >> 1;
    int quad = lane >> 4, lm = lane & 15;
    float m[8];
#pragma unroll
    for (int j = 0; j < 8; j++) m[j] = -INFINITY;
    for (int bxi = 0; bxi < NBX; bxi++) {
        int bx = g * NBX + bxi;
        float c0p[8], c1v[8];
#pragma unroll
        for (int cg = 0; cg < 2; cg++)
#pragma unroll
            for (int u = 0; u < 4; u++) {
                int q = bx * 128 + cg * 64 + u * 16 + lm;
                float2 cc = coef[q];
                c0p[cg * 4 + u] = cc.x - log2f(colsum[q]);
                c1v[cg * 4 + u] = cc.y;
            }
        const ushort_t* bb = sim + ((size_t)(by * NQB + bx)) * 16384
                           + (size_t)((t2 * 4) * 512 + quad * 128 + lm * 8);
#pragma unroll
        for (int cg = 0; cg < 2; cg++) {
            int slot = ph + 2 * cg;
#pragma unroll
            for (int u = 0; u < 4; u++) {
                ushort8_t e = *(const ushort8_t*)(bb + slot * 4096 + u * 512);
                float a = c0p[cg * 4 + u], c = c1v[cg * 4 + u];
#pragma unroll
                for (int j = 0; j < 8; j++) m[j] = fmaxf(m[j], a + c * bf2f(e.v[j]));
            }
        }
    }
    // reduce over the 16 lm lanes (they share the same p-set)
#pragma unroll
    for (int off = 1; off <= 8; off <<= 1)
#pragma unroll
        for (int j = 0; j < 8; j++) m[j] = fmaxf(m[j], __shfl_xor(m[j], off, 64));
    if (lm == 0) {
        int pbase = by * 128 + ph * 64 + t2 * 32 + quad * 4;
#pragma unroll
        for (int j = 0; j < 8; j++)
            rmPart[pbase + (j >> 2) * 16 + (j & 3)] = m[j];
    }
}

__global__ __launch_bounds__(256) void rowmax_all(
    const ushort_t* __restrict__ sim3, const float2* __restrict__ coef3, const float* __restrict__ colsum3,
    float* __restrict__ rmPart3,
    const ushort_t* __restrict__ sim4, const float2* __restrict__ coef4, const float* __restrict__ colsum4,
    float* __restrict__ rmPart4) {
    int bid = blockIdx.x;
    if (bid < 1024) {           // layer3: 4z * 32by * 8g
        int z = bid >> 8, rem = bid & 255, by = rem >> 3, g = rem & 7;
        rowmax_body<32, 4>(sim3 + (size_t)z * 16777216, coef3 + (size_t)z * 4096,
                           colsum3 + (size_t)z * 4096,
                           rmPart3 + ((size_t)(z * 8 + g)) * 4096, by, g);
    } else {                    // layer4: 4z * 8by * 4g
        bid -= 1024;
        int z = bid >> 5, rem = bid & 31, by = rem >> 2, g = rem & 3;
        rowmax_body<8, 2>(sim4 + (size_t)z * 1048576, coef4 + (size_t)z * 1024,
                          colsum4 + (size_t)z * 1024,
                          rmPart4 + ((size_t)(z * 4 + g)) * 1024, by, g);
    }
}

// ===== rowmax partial reduce -> exp2 -> acc =====
__global__ __launch_bounds__(256) void rmreduce_all(
    const float* __restrict__ rmPart3, const float* __restrict__ rmPart4,
    float* __restrict__ acc) {
    const float* rm; int G, stride, p; float* slot;
    int bid = blockIdx.x;
    if (bid < 64) {             // layer3: 4z * 16 blocks
        int z = bid >> 4, blk = bid & 15; G = 8; stride = 4096;
        rm = rmPart3 + (size_t)z * 8 * 4096;
        p = blk * 256 + threadIdx.x; slot = acc + z;
    } else {
        bid -= 64;              // layer4: 4z * 4 blocks
        int z = bid >> 2, blk = bid & 3; G = 4; stride = 1024;
        rm = rmPart4 + (size_t)z * 4 * 1024;
        p = blk * 256 + threadIdx.x; slot = acc + 4 + z;
    }
    float m = rm[p];
    for (int g = 1; g < G; g++) m = fmaxf(m, rm[(size_t)g * stride + p]);
    float k = exp2f(m);
#pragma unroll
    for (int off = 32; off >= 1; off >>= 1) k += __shfl_xor(k, off, 64);
    __shared__ float part[4];
    if ((threadIdx.x & 63) == 0) part[threadIdx.x >> 6] = k;
    __syncthreads();
    if (threadIdx.x == 0)
        atomicAdd(slot, part[0] + part[1] + part[2] + part[3]);
}

__global__ void finalize_kernel(const float* __restrict__ acc, float* __restrict__ out) {
    float loss = 0.f;
    for (int b = 0; b < 4; b++) loss += -logf(acc[b] * (1.f / 4096.f));
    for (int b = 0; b < 4; b++) loss += -2.f * logf(acc[4 + b] * (1.f / 1024.f));
    out[0] = loss;
}

extern "C" void kernel_launch(void* const* d_in, const int* in_sizes, int n_in,
                              void* d_out, int out_size, void* d_ws, size_t ws_size,
                              hipStream_t stream) {
    const float* gen3 = (const float*)d_in[0];
    const float* tar3 = (const float*)d_in[1];
    const float* gen4 = (const float*)d_in[2];
    const float* tar4 = (const float*)d_in[3];

    char* wsb = (char*)d_ws;
    size_t off = 0;
    auto alloc = [&](size_t bytes) {
        void* p = wsb + off;
        off += (bytes + 255) & ~(size_t)255;
        return p;
    };
    // layer3 (z=4): S=4096, C=256, R=64, nQB=32
    ushort_t* sim3 = (ushort_t*)alloc((size_t)4 * 16777216 * 2);   // 134.2 MB
    ushort_t* gnT3 = (ushort_t*)alloc((size_t)4 * 1048576 * 2);    // 8.4 MB
    ushort_t* tnT3 = (ushort_t*)alloc((size_t)4 * 1048576 * 2);    // 8.4 MB
    float* cmPart3 = (float*)alloc((size_t)4 * 262144 * 4);        // 4.2 MB
    float2* coef3 = (float2*)alloc((size_t)4 * 4096 * 8);
    float* colsum3 = (float*)alloc((size_t)4 * 4096 * 4);
    float* rmPart3 = (float*)alloc((size_t)4 * 8 * 4096 * 4);      // 512 KB
    // layer4 (z=4): S=1024, C=512, R=16, nQB=8
    ushort_t* sim4 = (ushort_t*)alloc((size_t)4 * 1048576 * 2);    // 8.4 MB
    ushort_t* gnT4 = (ushort_t*)alloc((size_t)4 * 524288 * 2);     // 4.2 MB
    ushort_t* tnT4 = (ushort_t*)alloc((size_t)4 * 524288 * 2);     // 4.2 MB
    float* cmPart4 = (float*)alloc((size_t)4 * 16384 * 4);
    float2* coef4 = (float2*)alloc((size_t)4 * 1024 * 8);
    float* colsum4 = (float*)alloc((size_t)4 * 1024 * 4);
    float* rmPart4 = (float*)alloc((size_t)4 * 4 * 1024 * 4);
    float* acc = (float*)alloc(64 * 4);
    // total ~173 MB (ws is 256 MiB)

    prep_all<<<256 + 1024, 256, 0, stream>>>(
        gen3, tar3, gen4, tar4, gnT3, tnT3, gnT4, tnT4);
    gemm_all<<<256 + 4096, 256, 0, stream>>>(
        tnT3, gnT3, sim3, cmPart3, tnT4, gnT4, sim4, cmPart4);
    colmax_reduce_all<<<16 + 64, 256, 0, stream>>>(
        cmPart3, coef3, colsum3, cmPart4, coef4, colsum4, acc);
    colsum_all<<<256 + 4096, 256, 0, stream>>>(
        sim3, coef3, colsum3, sim4, coef4, colsum4);
    rowmax_all<<<1024 + 128, 256, 0, stream>>>(
        sim3, coef3, colsum3, rmPart3, sim4, coef4, colsum4, rmPart4);
    rmreduce_all<<<64 + 16, 256, 0, stream>>>(rmPart3, rmPart4, acc);
    finalize_kernel<<<1, 1, 0, stream>>>(acc, (float*)d_out);
}